// Round 3
// baseline (215.693 us; speedup 1.0000x reference)
//
#include <hip/hip_runtime.h>

// ws layout:
//   u32 scal[0]: maxabs(x)      (f32 bits, atomicMax as u32 — values >= 0)
//   u32 scal[1]: maxabs(conv_w) (f32 bits)
//   u32 scal[2]: maxabs(fc_w)   (f32 bits)
//   u32 scal[3]: maxabs(flat)   (f32 bits, atomicMax as u32)
//   byte 256+ : flat buffer, 8192*576 f32 = 18,874,368 B
// scal[0..3] zeroed each launch via hipMemsetAsync (graph-safe).

#define DEV __device__ __forceinline__

// IEEE-exact quant index: clip(v/s, -7, 7) then round-half-even.
// MUST use true division (correctly rounded) to bit-match the reference;
// reciprocal-multiply can flip round-to-nearest-even ties.
DEV float quantq(float v, float s) {
  return rintf(fminf(7.0f, fmaxf(-7.0f, v / s)));
}

DEV float block_reduce_max(float v, float* smem) {
#pragma unroll
  for (int off = 32; off > 0; off >>= 1)
    v = fmaxf(v, __shfl_xor(v, off, 64));
  __syncthreads();
  if ((threadIdx.x & 63) == 0) smem[threadIdx.x >> 6] = v;
  __syncthreads();
  float m = smem[0];
  for (int i = 1; i < ((int)blockDim.x >> 6); ++i) m = fmaxf(m, smem[i]);
  return m;
}

// Grid-stride maxabs over x (atomicMax into scal[0]); block 0 additionally
// reduces the two weight tensors (plain stores to scal[1], scal[2]).
__global__ __launch_bounds__(256) void maxabs_kernel(
    const float4* __restrict__ x4, int n4, const float* __restrict__ cw,
    const float* __restrict__ fw, unsigned int* __restrict__ scal) {
  __shared__ float smem[8];
  float m = 0.f;
  for (int i = blockIdx.x * blockDim.x + threadIdx.x; i < n4;
       i += gridDim.x * blockDim.x) {
    float4 v = x4[i];
    m = fmaxf(m, fmaxf(fmaxf(fabsf(v.x), fabsf(v.y)),
                       fmaxf(fabsf(v.z), fabsf(v.w))));
  }
  m = block_reduce_max(m, smem);
  if (threadIdx.x == 0) atomicMax(scal + 0, __float_as_uint(m));
  if (blockIdx.x == 0) {
    const int tid = threadIdx.x;
    float m1 = 0.f;
    for (int i = tid; i < 144; i += 256) m1 = fmaxf(m1, fabsf(cw[i]));
    m1 = block_reduce_max(m1, smem);
    float m2 = 0.f;
    for (int i = tid; i < 5760; i += 256) m2 = fmaxf(m2, fabsf(fw[i]));
    m2 = block_reduce_max(m2, smem);
    if (tid == 0) {
      scal[1] = __float_as_uint(m1);
      scal[2] = __float_as_uint(m2);
    }
  }
}

// One image per block, 576 threads: thread = (channel c = tid/36, pooled-pos
// pp = tid%36). Stage quantized x (784 f32) + weights in LDS; each thread
// loads its 6x6 patch into registers (b128/b64 LDS reads) and computes one
// pooled output. flat[b*576+tid] is a fully coalesced store (tid == c*36+pp
// == torch flatten order). Conv accumulation exact (integer f32, |sum|<=441);
// ReLU folded into pool-max (m starts at 0).
__global__ __launch_bounds__(576) void conv_pool_kernel(
    const float* __restrict__ x, const float* __restrict__ cw,
    const float* __restrict__ cb, unsigned int* __restrict__ scal,
    float* __restrict__ flat) {
  __shared__ __align__(16) float qx[784];
  __shared__ float qw[144];
  __shared__ float bias[16];
  __shared__ float smem[16];
  const int tid = threadIdx.x;
  const int b = blockIdx.x;
  const float sx = __uint_as_float(scal[0]) / 7.0f + 1e-8f;
  const float sw = __uint_as_float(scal[1]) / 7.0f + 1e-8f;
  const float sxw = sx * sw;
  if (tid < 196) {
    float4 v = ((const float4*)x)[b * 196 + tid];
    float4 q;
    q.x = quantq(v.x, sx); q.y = quantq(v.y, sx);
    q.z = quantq(v.z, sx); q.w = quantq(v.w, sx);
    ((float4*)qx)[tid] = q;
  } else if (tid < 340) {
    const int i = tid - 196;
    qw[i] = quantq(cw[i], sw);
  } else if (tid < 356) {
    bias[tid - 340] = cb[tid - 340];
  }
  __syncthreads();
  const int c = tid / 36, pp = tid % 36, pi = pp / 6, pj = pp % 6;
  float w[9];
#pragma unroll
  for (int i = 0; i < 9; ++i) w[i] = qw[c * 9 + i];  // broadcast across pp
  const float bc = bias[c];
  const float* base = &qx[pi * 112 + pj * 4];  // 16B-aligned
  float r[36];
#pragma unroll
  for (int rr = 0; rr < 6; ++rr) {
    const float4 v4 = *(const float4*)(base + rr * 28);
    const float2 v2 = *(const float2*)(base + rr * 28 + 4);
    r[rr * 6 + 0] = v4.x; r[rr * 6 + 1] = v4.y; r[rr * 6 + 2] = v4.z;
    r[rr * 6 + 3] = v4.w; r[rr * 6 + 4] = v2.x; r[rr * 6 + 5] = v2.y;
  }
  float m = 0.f;  // ReLU folded in
#pragma unroll
  for (int dr = 0; dr < 4; ++dr)
#pragma unroll
    for (int dc = 0; dc < 4; ++dc) {
      const float* q = &r[dr * 6 + dc];
      float acc = q[0] * w[0] + q[1] * w[1] + q[2] * w[2]
                + q[6] * w[3] + q[7] * w[4] + q[8] * w[5]
                + q[12] * w[6] + q[13] * w[7] + q[14] * w[8];
      m = fmaxf(m, acc * sxw + bc);
    }
  flat[b * 576 + tid] = m;
  float lmax = block_reduce_max(m, smem);  // m >= 0
  if (tid == 0) atomicMax(scal + 3, __float_as_uint(lmax));
}

// One WAVE per image (2048 blocks x 4 waves). Lanes read flat coalesced
// (k = j*64 + lane); quantized fc_w staged in LDS; butterfly reduce the 10
// accumulators. Integer dot (<= 28224) exact in f32.
__global__ __launch_bounds__(256) void fc_kernel(
    const float* __restrict__ flat, const float* __restrict__ fw,
    const float* __restrict__ fb, const unsigned int* __restrict__ scal,
    float* __restrict__ out) {
  __shared__ float qfw[5760];
  __shared__ float sb[10];
  const float sf = __uint_as_float(scal[3]) / 7.0f + 1e-8f;
  const float sfw = __uint_as_float(scal[2]) / 7.0f + 1e-8f;
  const int tid = threadIdx.x;
  for (int i = tid; i < 5760; i += 256) qfw[i] = quantq(fw[i], sfw);
  if (tid < 10) sb[tid] = fb[tid];
  __syncthreads();
  const int wave = tid >> 6, lane = tid & 63;
  const int b = blockIdx.x * 4 + wave;
  float acc[10];
#pragma unroll
  for (int o = 0; o < 10; ++o) acc[o] = 0.f;
  const float* frow = &flat[b * 576];
#pragma unroll
  for (int j = 0; j < 9; ++j) {
    const int k = j * 64 + lane;
    const float qf = quantq(frow[k], sf);
#pragma unroll
    for (int o = 0; o < 10; ++o) acc[o] += qf * qfw[o * 576 + k];
  }
#pragma unroll
  for (int o = 0; o < 10; ++o)
#pragma unroll
    for (int off = 32; off > 0; off >>= 1)
      acc[o] += __shfl_xor(acc[o], off, 64);
  if (lane == 0) {
    const float ss = sf * sfw;
#pragma unroll
    for (int o = 0; o < 10; ++o) out[b * 10 + o] = acc[o] * ss + sb[o];
  }
}

extern "C" void kernel_launch(void* const* d_in, const int* in_sizes, int n_in,
                              void* d_out, int out_size, void* d_ws, size_t ws_size,
                              hipStream_t stream) {
  const float* x  = (const float*)d_in[0];
  const float* cw = (const float*)d_in[1];
  const float* cb = (const float*)d_in[2];
  const float* fw = (const float*)d_in[3];
  const float* fb = (const float*)d_in[4];
  float* out = (float*)d_out;
  unsigned int* scal = (unsigned int*)d_ws;
  float* flat = (float*)((char*)d_ws + 256);

  hipMemsetAsync(scal, 0, 16, stream);  // zero atomic slots (graph-safe)
  maxabs_kernel<<<2048, 256, 0, stream>>>(
      (const float4*)x, (8192 * 784) / 4, cw, fw, scal);
  conv_pool_kernel<<<8192, 576, 0, stream>>>(x, cw, cb, scal, flat);
  fc_kernel<<<2048, 256, 0, stream>>>(flat, fw, fb, scal, out);
}

// Round 4
// 136.611 us; speedup vs baseline: 1.5789x; 1.5789x over previous
//
#include <hip/hip_runtime.h>
#include <stdint.h>

// ws layout (bytes):
//   0..15    u32 scal[4]: maxabs bits of {x, conv_w, fc_w, flat} (f32 bits; >=0
//            so u32 atomicMax == float max). scal[0],scal[3] via atomicMax
//            (pre-zeroed by hipMemsetAsync); scal[1],scal[2] plain stores.
//   64..     u32 wpk[48]:   conv w packed i8 [c][kr] = [w0,w1,w2,0]
//   256..    u32 qfwp[1440]: fc w packed i8 [o][g], g = k/4
//   8192..   f32 flat[8192*576]
// Total 8192 + 18,874,368 B — within the ws budget proven in rounds 1-3.

#define DEV __device__ __forceinline__

// IEEE-exact quant index: clip(v/s,-7,7), round-half-even, to int.
// True division required to bit-match the reference (tie-sensitive).
DEV int quanti(float v, float s) {
  return (int)rintf(fminf(7.0f, fmaxf(-7.0f, v / s)));
}

#if __has_builtin(__builtin_amdgcn_sdot4)
DEV int dot4(int a, int b, int c) { return __builtin_amdgcn_sdot4(a, b, c, false); }
#else
DEV int dot4(int a, int b, int c) {
  c += (int)(int8_t)(a)       * (int)(int8_t)(b);
  c += (int)(int8_t)(a >> 8)  * (int)(int8_t)(b >> 8);
  c += (int)(int8_t)(a >> 16) * (int)(int8_t)(b >> 16);
  c += (int)(int8_t)(a >> 24) * (int)(int8_t)(b >> 24);
  return c;
}
#endif

DEV uint32_t pk4(int q0, int q1, int q2, int q3) {
  return (uint32_t)(q0 & 255) | ((uint32_t)(q1 & 255) << 8) |
         ((uint32_t)(q2 & 255) << 16) | ((uint32_t)(q3 & 255) << 24);
}

DEV float block_reduce_max(float v, float* smem) {
#pragma unroll
  for (int off = 32; off > 0; off >>= 1)
    v = fmaxf(v, __shfl_xor(v, off, 64));
  __syncthreads();
  if ((threadIdx.x & 63) == 0) smem[threadIdx.x >> 6] = v;
  __syncthreads();
  float m = smem[0];
  for (int i = 1; i < ((int)blockDim.x >> 6); ++i) m = fmaxf(m, smem[i]);
  return m;
}

// Grid-stride maxabs over x (atomicMax -> scal[0]); block 0 additionally
// reduces both weight tensors and quantize-packs them to i8 (done ONCE here,
// not per-block in conv/fc).
__global__ __launch_bounds__(256) void maxabs_pack_kernel(
    const float4* __restrict__ x4, int n4, const float* __restrict__ cw,
    const float* __restrict__ fw, unsigned int* __restrict__ scal,
    uint32_t* __restrict__ wpk, uint32_t* __restrict__ qfwp) {
  __shared__ float smem[4];
  const int tid = threadIdx.x;
  float m = 0.f;
  for (int i = blockIdx.x * blockDim.x + tid; i < n4;
       i += gridDim.x * blockDim.x) {
    float4 v = x4[i];
    m = fmaxf(m, fmaxf(fmaxf(fabsf(v.x), fabsf(v.y)),
                       fmaxf(fabsf(v.z), fabsf(v.w))));
  }
  m = block_reduce_max(m, smem);
  if (tid == 0) atomicMax(scal + 0, __float_as_uint(m));
  if (blockIdx.x == 0) {
    float m1 = 0.f;
    for (int i = tid; i < 144; i += 256) m1 = fmaxf(m1, fabsf(cw[i]));
    m1 = block_reduce_max(m1, smem);
    float m2 = 0.f;
    for (int i = tid; i < 5760; i += 256) m2 = fmaxf(m2, fabsf(fw[i]));
    m2 = block_reduce_max(m2, smem);
    if (tid == 0) {
      scal[1] = __float_as_uint(m1);
      scal[2] = __float_as_uint(m2);
    }
    const float sw = m1 / 7.0f + 1e-8f;
    const float sfw = m2 / 7.0f + 1e-8f;
    if (tid < 48) {  // conv w: [c][kr] -> bytes [w0,w1,w2,0]
      const int c = tid / 3, kr = tid % 3;
      const float* p = cw + c * 9 + kr * 3;
      wpk[tid] = pk4(quanti(p[0], sw), quanti(p[1], sw), quanti(p[2], sw), 0);
    }
    for (int i = tid; i < 1440; i += 256) {  // fc w: [o][g], k = 4g..4g+3
      const int o = i / 144, g = i - o * 144;
      const float* p = fw + o * 576 + g * 4;
      qfwp[i] = pk4(quanti(p[0], sfw), quanti(p[1], sfw),
                    quanti(p[2], sfw), quanti(p[3], sfw));
    }
  }
}

// Thread = (img, pooled-pos). No LDS staging, no barriers (patch read direct
// from global; 6.4MB quantized-equivalent footprint is cache-friendly).
// Quantize the 6x6 patch once -> packed i8 dwords a[row][dc] (bytes dc..dc+3);
// all 16 channels via 3x sdot4 per window (integer-exact, |sum|<=441).
// Pool-max in int domain (sxw>0: max commutes with positive-affine); ReLU via
// fmaxf(.,0). flat bits identical to rounds 1-3.
__global__ __launch_bounds__(256) void conv_pool_kernel(
    const float* __restrict__ x, const float* __restrict__ cb,
    unsigned int* __restrict__ scal, const uint32_t* __restrict__ wpk,
    float* __restrict__ flat) {
  __shared__ float smem[4];
  const int gid = blockIdx.x * 256 + threadIdx.x;  // < 8192*36 exactly
  const int img = gid / 36, pp = gid - img * 36;
  const int pi = pp / 6, pj = pp - pi * 6;
  const float sx = __uint_as_float(scal[0]) / 7.0f + 1e-8f;
  const float sw = __uint_as_float(scal[1]) / 7.0f + 1e-8f;
  const float sxw = sx * sw;
  const float* base = x + img * 784 + pi * 112 + pj * 4;  // 16B-aligned
  uint32_t a[6][4];
#pragma unroll
  for (int rr = 0; rr < 6; ++rr) {
    const float4 v4 = *(const float4*)(base + rr * 28);
    const float2 v2 = *(const float2*)(base + rr * 28 + 4);
    const uint32_t lo = pk4(quanti(v4.x, sx), quanti(v4.y, sx),
                            quanti(v4.z, sx), quanti(v4.w, sx));
    const uint32_t hi = pk4(quanti(v2.x, sx), quanti(v2.y, sx), 0, 0);
    const uint64_t r8 = (uint64_t)lo | ((uint64_t)hi << 32);
    a[rr][0] = lo;
    a[rr][1] = (uint32_t)(r8 >> 8);
    a[rr][2] = (uint32_t)(r8 >> 16);
    a[rr][3] = (uint32_t)(r8 >> 24);
  }
  float lmax = 0.f;
  float* fo = &flat[img * 576 + pp];
#pragma unroll
  for (int c = 0; c < 16; ++c) {
    const uint32_t w0 = wpk[c * 3 + 0], w1 = wpk[c * 3 + 1], w2 = wpk[c * 3 + 2];
    int acc[16];
#pragma unroll
    for (int dr = 0; dr < 4; ++dr)
#pragma unroll
      for (int dc = 0; dc < 4; ++dc) {
        int s_ = dot4(a[dr][dc], w0, 0);
        s_ = dot4(a[dr + 1][dc], w1, s_);
        s_ = dot4(a[dr + 2][dc], w2, s_);
        acc[dr * 4 + dc] = s_;
      }
    int mi = acc[0];
#pragma unroll
    for (int i = 1; i < 16; ++i) mi = max(mi, acc[i]);
    const float v = fmaxf((float)mi * sxw + cb[c], 0.f);  // +bias, ReLU
    fo[c * 36] = v;
    lmax = fmaxf(lmax, v);  // v >= 0
  }
  lmax = block_reduce_max(lmax, smem);
  if (threadIdx.x == 0) atomicMax(scal + 3, __float_as_uint(lmax));
}

// One WAVE per image. flat read as coalesced float4 (g = k/4); quantize 4
// elems -> packed i8; 10x sdot4 vs prepacked fc weights (staged u32 copy, no
// divides). Integer dot (<=28224) exact; out bits identical to rounds 1-3.
__global__ __launch_bounds__(256) void fc_kernel(
    const float* __restrict__ flat, const uint32_t* __restrict__ qfwp,
    const float* __restrict__ fb, const unsigned int* __restrict__ scal,
    float* __restrict__ out) {
  __shared__ uint32_t qw[1440];
  __shared__ float sb[10];
  const int tid = threadIdx.x;
  for (int i = tid; i < 1440; i += 256) qw[i] = qfwp[i];
  if (tid < 10) sb[tid] = fb[tid];
  __syncthreads();
  const float sf = __uint_as_float(scal[3]) / 7.0f + 1e-8f;
  const float sfw = __uint_as_float(scal[2]) / 7.0f + 1e-8f;
  const int wave = tid >> 6, lane = tid & 63;
  const int b = blockIdx.x * 4 + wave;
  int acc[10];
#pragma unroll
  for (int o = 0; o < 10; ++o) acc[o] = 0;
#pragma unroll
  for (int j = 0; j < 3; ++j) {
    const int g = j * 64 + lane;
    if (g < 144) {
      const float4 v = *(const float4*)(flat + b * 576 + g * 4);
      const uint32_t pq = pk4(quanti(v.x, sf), quanti(v.y, sf),
                              quanti(v.z, sf), quanti(v.w, sf));
#pragma unroll
      for (int o = 0; o < 10; ++o) acc[o] = dot4(pq, qw[o * 144 + g], acc[o]);
    }
  }
#pragma unroll
  for (int o = 0; o < 10; ++o)
#pragma unroll
    for (int off = 32; off > 0; off >>= 1)
      acc[o] += __shfl_xor(acc[o], off, 64);
  if (lane == 0) {
    const float ss = sf * sfw;
#pragma unroll
    for (int o = 0; o < 10; ++o) out[b * 10 + o] = (float)acc[o] * ss + sb[o];
  }
}

extern "C" void kernel_launch(void* const* d_in, const int* in_sizes, int n_in,
                              void* d_out, int out_size, void* d_ws, size_t ws_size,
                              hipStream_t stream) {
  const float* x  = (const float*)d_in[0];
  const float* cw = (const float*)d_in[1];
  const float* cb = (const float*)d_in[2];
  const float* fw = (const float*)d_in[3];
  const float* fb = (const float*)d_in[4];
  float* out = (float*)d_out;
  unsigned int* scal = (unsigned int*)d_ws;
  uint32_t* wpk  = (uint32_t*)((char*)d_ws + 64);
  uint32_t* qfwp = (uint32_t*)((char*)d_ws + 256);
  float* flat    = (float*)((char*)d_ws + 8192);

  hipMemsetAsync(scal, 0, 16, stream);  // zero atomic slots (graph-safe)
  maxabs_pack_kernel<<<2048, 256, 0, stream>>>(
      (const float4*)x, (8192 * 784) / 4, cw, fw, scal, wpk, qfwp);
  conv_pool_kernel<<<(8192 * 36) / 256, 256, 0, stream>>>(x, cb, scal, wpk, flat);
  fc_kernel<<<2048, 256, 0, stream>>>(flat, qfwp, fb, scal, out);
}